// Round 4
// baseline (747.674 us; speedup 1.0000x reference)
//
#include <hip/hip_runtime.h>
#include <hip/hip_bf16.h>
#include <stdint.h>

#define N_TOKENS 100000
#define N_ARGS   20000
#define N_EDGES  320000
#define IN_DIM   768
#define HEADS    8
#define OUT_DIM  64
#define ZDIM     512   // HEADS*OUT_DIM

typedef unsigned short u16;
typedef unsigned int   u32;
typedef __bf16 bf16x8 __attribute__((ext_vector_type(8)));
typedef float  f32x4  __attribute__((ext_vector_type(4)));

__device__ __forceinline__ u16 f2bf(float f) {
    union { float f; u32 i; } v; v.f = f;
    u32 u = v.i;
    u += 0x7fffu + ((u >> 16) & 1u);   // RNE
    return (u16)(u >> 16);
}
__device__ __forceinline__ float bf2f(u16 u) {
    union { u32 i; float f; } v; v.i = ((u32)u) << 16; return v.f;
}
__device__ __forceinline__ u32 pk(float lo, float hi) {
    __hip_bfloat162 r = __float22bfloat162_rn(float2{lo, hi});
    union { __hip_bfloat162 b; u32 u; } v; v.b = r; return v.u;
}
__device__ __forceinline__ uint4 pack8(const float4 p, const float4 q) {
    uint4 w;
    w.x = pk(p.x, p.y); w.y = pk(p.z, p.w);
    w.z = pk(q.x, q.y); w.w = pk(q.z, q.w);
    return w;
}
// async global->LDS DMA, 16B per lane; LDS dest = wave-uniform base + lane*16
__device__ __forceinline__ void load_lds16(const void* g, void* l) {
    __builtin_amdgcn_global_load_lds(
        (const __attribute__((address_space(1))) void*)g,
        (__attribute__((address_space(3))) void*)l, 16, 0, 0);
}

// ---------------------------------------------------------------------------
// W fp32 -> bf16 (one-time, 786 KB)
// ---------------------------------------------------------------------------
__global__ __launch_bounds__(256) void convert_w(const float* __restrict__ W,
                                                 u16* __restrict__ Wbf) {
    const int i = blockIdx.x * blockDim.x + threadIdx.x;   // 8-elem chunk idx
    if (i < ZDIM * IN_DIM / 8) {
        const float4* p = reinterpret_cast<const float4*>(W + (size_t)i * 8);
        const float4 x = p[0], y = p[1];
        reinterpret_cast<uint4*>(Wbf)[i] = pack8(x, y);
    }
}

// ---------------------------------------------------------------------------
// GEMM: z[M,512] = h[M,768] @ W[512,768]^T
// Round-4: 128x256 tile (2 tileN slices instead of 4) -> the A panel
// transits the L3/L2 path 2x instead of 4x (staged volume 1.8 GB -> 1.2 GB)
// and barrier-steps per output halve. Machinery identical to the verified
// round-2 kernel: single-buffered LDS, two barriers per K-step, DMA staging
// with source-side XOR swizzle, same read swizzles. 4 waves, wave = 64x128
// output = 4x8 16x16 frags (acc 128 VGPR; bF processed 4-at-a-time).
// ---------------------------------------------------------------------------
__global__ __launch_bounds__(256) void gemm_kernel(
    const float* __restrict__ A,      // h [M, K] fp32
    const u16*   __restrict__ Bbf,    // W [512, K] bf16
    const float* __restrict__ a_attn, // [128] fp32, use first 64
    u16* __restrict__ z,              // [M, 512] bf16
    float* __restrict__ s_node)       // [M, 8] fp32
{
    __shared__ float As[128 * 32];    // 16 KB
    __shared__ u16   Bs[256 * 32];    // 16 KB

    const int tid  = threadIdx.x;
    const int wave = tid >> 6, lane = tid & 63;
    const int quad = lane >> 4, l16 = lane & 15;
    const int wm = wave >> 1, wn = wave & 1;

    // XCD-aware bijective swizzle: grid 1568 = 8 XCDs * 196; 4 dead blocks.
    const int bx = blockIdx.x;
    const int lb = (bx & 7) * 196 + (bx >> 3);
    if (lb >= 782 * 2) return;
    const int tileN2 = lb & 1;        // 2 slices of 256 cols
    const int tileM  = lb >> 1;

    // ---- DMA plumbing: A = 1024 slots of 16B (8/row), B = 1024 (4/row)
    const char* srcA[4];
    int         dA[4];
#pragma unroll
    for (int g = 0; g < 4; g++) {
        const int idx = (wave * 4 + g) * 64 + lane;    // 16B slot index in As
        const int row = idx >> 3, s = idx & 7;
        const int c = s ^ (row & 7);                   // source 16B chunk
        int grow = tileM * 128 + row;
        if (grow >= N_TOKENS) grow = N_TOKENS - 1;
        srcA[g] = (const char*)(A + (size_t)grow * IN_DIM + c * 4);
        dA[g] = (wave * 4 + g) * 1024;
    }
    const char* srcB[4];
    int         dB[4];
#pragma unroll
    for (int g = 0; g < 4; g++) {
        const int idx = (wave * 4 + g) * 64 + lane;    // 16B slot index in Bs
        const int row = idx >> 2, s = idx & 3;
        const int c = s ^ ((row >> 1) & 3);
        srcB[g] = (const char*)(Bbf + (size_t)(tileN2 * 256 + row) * IN_DIM + c * 8);
        dB[g] = (wave * 4 + g) * 1024;
    }

    // ---- LDS read pointers (swizzled fragment layout)
    const float* rA0[4];
    const float* rA1[4];
    const u16*   rB[8];
#pragma unroll
    for (int i = 0; i < 4; i++) {
        const int r = wm * 64 + i * 16 + l16;
        const int sl = (quad * 2) ^ (r & 7);
        rA0[i] = As + r * 32 + sl * 4;          // k = quad*8 .. +3
        rA1[i] = As + r * 32 + (sl ^ 1) * 4;    // k = quad*8+4 .. +7
    }
#pragma unroll
    for (int j = 0; j < 8; j++) {
        const int r = wn * 128 + j * 16 + l16;
        rB[j] = Bs + r * 32 + ((quad ^ ((r >> 1) & 3)) * 8);
    }

    f32x4 acc[4][8];
    const f32x4 zero4 = {0.f, 0.f, 0.f, 0.f};
#pragma unroll
    for (int i = 0; i < 4; i++)
#pragma unroll
        for (int j = 0; j < 8; j++) acc[i][j] = zero4;

    for (int kt = 0; kt < IN_DIM / 32; ++kt) {
        __syncthreads();   // previous iteration's LDS reads complete
#pragma unroll
        for (int g = 0; g < 4; g++) load_lds16(srcA[g], (char*)As + dA[g]);
#pragma unroll
        for (int g = 0; g < 4; g++) load_lds16(srcB[g], (char*)Bs + dB[g]);
        __syncthreads();   // vmcnt(0) drain: staged tile visible

        bf16x8 aF[4];
#pragma unroll
        for (int i = 0; i < 4; i++) {
            const float4 lo = *reinterpret_cast<const float4*>(rA0[i]);
            const float4 hi = *reinterpret_cast<const float4*>(rA1[i]);
            union { uint4 u; bf16x8 b; } cv;
            cv.u = pack8(lo, hi);
            aF[i] = cv.b;
        }
        // j processed in two halves of 4 to cap live bF registers
#pragma unroll
        for (int jj = 0; jj < 2; jj++) {
            bf16x8 bF[4];
#pragma unroll
            for (int j = 0; j < 4; j++)
                bF[j] = *reinterpret_cast<const bf16x8*>(rB[jj * 4 + j]);
#pragma unroll
            for (int i = 0; i < 4; i++)
#pragma unroll
                for (int j = 0; j < 4; j++)
                    acc[i][jj * 4 + j] = __builtin_amdgcn_mfma_f32_16x16x32_bf16(
                        aF[i], bF[j], acc[i][jj * 4 + j], 0, 0, 0);
        }

#pragma unroll
        for (int g = 0; g < 4; g++) srcA[g] += 128;   // +32 f32
#pragma unroll
        for (int g = 0; g < 4; g++) srcB[g] += 64;    // +32 bf16
    }

    // epilogue: store bf16 z; fused s_node (wave covers heads hb, hb+1)
    float av[4];
#pragma unroll
    for (int j = 0; j < 4; j++) av[j] = a_attn[j * 16 + l16];
    const int hb   = tileN2 * 4 + wn * 2;
    const int colb = tileN2 * 256 + wn * 128;
#pragma unroll
    for (int i = 0; i < 4; i++) {
        const int rowb = tileM * 128 + wm * 64 + i * 16 + quad * 4;
#pragma unroll
        for (int r = 0; r < 4; r++) {
            const int row = rowb + r;
            const bool ok = row < N_TOKENS;
            float p0 = 0.0f, p1 = 0.0f;
#pragma unroll
            for (int j = 0; j < 4; j++) {
                const float v = acc[i][j][r];
                p0 += v * av[j];
                if (ok) z[(size_t)row * ZDIM + colb + j * 16 + l16] = f2bf(v);
            }
#pragma unroll
            for (int j = 0; j < 4; j++) {
                const float v = acc[i][4 + j][r];
                p1 += v * av[j];
                if (ok) z[(size_t)row * ZDIM + colb + 64 + j * 16 + l16] = f2bf(v);
            }
            p0 += __shfl_xor(p0, 1); p1 += __shfl_xor(p1, 1);
            p0 += __shfl_xor(p0, 2); p1 += __shfl_xor(p1, 2);
            p0 += __shfl_xor(p0, 4); p1 += __shfl_xor(p1, 4);
            p0 += __shfl_xor(p0, 8); p1 += __shfl_xor(p1, 8);
            if (ok && l16 == 0) {
                s_node[row * HEADS + hb]     = p0;
                s_node[row * HEADS + hb + 1] = p1;
            }
        }
    }
}

// ---------------------------------------------------------------------------
// CSR build (bounds-guarded)
// ---------------------------------------------------------------------------
__global__ void zero_kernel(int* __restrict__ p, int n) {
    int i = blockIdx.x * blockDim.x + threadIdx.x;
    if (i < n) p[i] = 0;
}

__global__ void hist_kernel(const int* __restrict__ edst, int* __restrict__ counts) {
    int i = blockIdx.x * blockDim.x + threadIdx.x;
    if (i < N_EDGES) {
        int d = edst[i];
        if ((unsigned)d < (unsigned)N_ARGS) atomicAdd(&counts[d], 1);
    }
}

// Round-4 scan: LDS-staged so global reads/writes are coalesced (old version
// did stride-20 scalar accesses from a single block).
__global__ void scan_kernel(const int* __restrict__ counts, int* __restrict__ offsets,
                            int* __restrict__ cursor) {
    __shared__ int cbuf[N_ARGS];      // 80 KB
    __shared__ int partial[1024];
    const int tid = threadIdx.x;
    for (int i = tid; i < N_ARGS; i += 1024) cbuf[i] = counts[i];
    __syncthreads();
    const int C = 20;                 // 1024*20 >= 20000
    const int base = tid * C;
    int s = 0;
#pragma unroll
    for (int k = 0; k < C; k++) { int idx = base + k; if (idx < N_ARGS) s += cbuf[idx]; }
    partial[tid] = s;
    __syncthreads();
    for (int off = 1; off < 1024; off <<= 1) {
        int v = (tid >= off) ? partial[tid - off] : 0;
        __syncthreads();
        partial[tid] += v;
        __syncthreads();
    }
    const int total = partial[1023];
    int run = (tid == 0) ? 0 : partial[tid - 1];
#pragma unroll
    for (int k = 0; k < C; k++) {
        int idx = base + k;
        if (idx < N_ARGS) { int c = cbuf[idx]; cbuf[idx] = run; run += c; }
    }
    __syncthreads();
    for (int i = tid; i < N_ARGS; i += 1024) {
        const int v = cbuf[i];
        offsets[i] = v;
        cursor[i]  = v;
    }
    if (tid == 1023) offsets[N_ARGS] = total;
}

__global__ void scatter_kernel(const int* __restrict__ esrc, const int* __restrict__ edst,
                               int* __restrict__ cursor, int* __restrict__ ssrc) {
    int i = blockIdx.x * blockDim.x + threadIdx.x;
    if (i < N_EDGES) {
        int d = edst[i];
        if ((unsigned)d >= (unsigned)N_ARGS) return;
        int s = esrc[i];
        if ((unsigned)s >= (unsigned)N_TOKENS) s = 0;
        int pos = atomicAdd(&cursor[d], 1);
        ssrc[pos] = s;
    }
}

// ---------------------------------------------------------------------------
// agg: ONE WAVE per dst (4 dsts/block), barrier-free (round-3, verified).
// ---------------------------------------------------------------------------
__global__ __launch_bounds__(256) void agg_kernel(
    const int* __restrict__ offsets, const int* __restrict__ sorted_src,
    const float* __restrict__ s_node, const u16* __restrict__ z,
    float* __restrict__ out)
{
    const int tid  = threadIdx.x;
    const int wave = tid >> 6, lane = tid & 63;
    const int dst  = blockIdx.x * 4 + wave;

    __shared__ int   src_s[4][64];
    __shared__ float alpha_s[4][512];

    if (dst >= N_ARGS) return;

    const int start = offsets[dst];
    const int nE = offsets[dst + 1] - start;
    float* op = out + (size_t)dst * ZDIM + lane * 8;
    if (nE <= 0) {
        const f32x4 zz = {0.f, 0.f, 0.f, 0.f};
        *reinterpret_cast<f32x4*>(op)     = zz;
        *reinterpret_cast<f32x4*>(op + 4) = zz;
        return;
    }
    int*   srcw = src_s[wave];
    float* alw  = alpha_s[wave];
    const int hsel = lane >> 3;   // head owning this lane's 8 cols

    // ---- pass A: online per-head max + denom (exact: final m is global max)
    float m[8], ssum[8];
#pragma unroll
    for (int h = 0; h < 8; h++) { m[h] = -1e30f; ssum[h] = 0.f; }

    for (int c0 = 0; c0 < nE; c0 += 64) {
        float v[8];
        const bool act = (c0 + lane) < nE;
        if (act) {
            int s = sorted_src[start + c0 + lane];
            if ((unsigned)s >= (unsigned)N_TOKENS) s = 0;
            const float4* p = reinterpret_cast<const float4*>(s_node + (size_t)s * 8);
            const float4 x = p[0], y = p[1];
            v[0]=x.x; v[1]=x.y; v[2]=x.z; v[3]=x.w;
            v[4]=y.x; v[5]=y.y; v[6]=y.z; v[7]=y.w;
#pragma unroll
            for (int h = 0; h < 8; h++) v[h] = v[h] > 0.f ? v[h] : 0.01f * v[h];
        } else {
#pragma unroll
            for (int h = 0; h < 8; h++) v[h] = -1e30f;
        }
        float cm[8];
#pragma unroll
        for (int h = 0; h < 8; h++) cm[h] = v[h];
#pragma unroll
        for (int off = 1; off < 64; off <<= 1)
#pragma unroll
            for (int h = 0; h < 8; h++) cm[h] = fmaxf(cm[h], __shfl_xor(cm[h], off));
        float ce[8];
#pragma unroll
        for (int h = 0; h < 8; h++) {
            const float mn = fmaxf(m[h], cm[h]);
            ce[h] = act ? __expf(v[h] - mn) : 0.f;
            ssum[h] *= __expf(m[h] - mn);
            m[h] = mn;
        }
#pragma unroll
        for (int off = 1; off < 64; off <<= 1)
#pragma unroll
            for (int h = 0; h < 8; h++) ce[h] += __shfl_xor(ce[h], off);
#pragma unroll
        for (int h = 0; h < 8; h++) ssum[h] += ce[h];
    }
    float inv[8];
#pragma unroll
    for (int h = 0; h < 8; h++) {
        float d = ssum[h]; if (d == 0.f) d = 1.f; inv[h] = 1.f / d;
    }

    // ---- pass B: alpha -> LDS, then per-edge weighted gather of z rows
    f32x4 acc0 = {0.f,0.f,0.f,0.f}, acc1 = {0.f,0.f,0.f,0.f};
    for (int c0 = 0; c0 < nE; c0 += 64) {
        const int cn = min(64, nE - c0);
        if (lane < cn) {
            int s = sorted_src[start + c0 + lane];
            if ((unsigned)s >= (unsigned)N_TOKENS) s = 0;
            srcw[lane] = s;
            const float4* p = reinterpret_cast<const float4*>(s_node + (size_t)s * 8);
            const float4 x = p[0], y = p[1];
            float v[8];
            v[0]=x.x; v[1]=x.y; v[2]=x.z; v[3]=x.w;
            v[4]=y.x; v[5]=y.y; v[6]=y.z; v[7]=y.w;
#pragma unroll
            for (int h = 0; h < 8; h++) {
                const float u = v[h] > 0.f ? v[h] : 0.01f * v[h];
                alw[lane * 8 + h] = __expf(u - m[h]) * inv[h];
            }
        }
        // wave-internal LDS visibility (no cross-wave sharing -> no barrier)
        asm volatile("s_waitcnt lgkmcnt(0)" ::: "memory");
        for (int j = 0; j < cn; ++j) {
            const int   row = srcw[j];
            const float a   = alw[j * 8 + hsel];
            const uint4 zr  = *reinterpret_cast<const uint4*>(
                                  z + (size_t)row * ZDIM + lane * 8);
            acc0.x += a * bf2f((u16)(zr.x & 0xffffu));
            acc0.y += a * bf2f((u16)(zr.x >> 16));
            acc0.z += a * bf2f((u16)(zr.y & 0xffffu));
            acc0.w += a * bf2f((u16)(zr.y >> 16));
            acc1.x += a * bf2f((u16)(zr.z & 0xffffu));
            acc1.y += a * bf2f((u16)(zr.z >> 16));
            acc1.z += a * bf2f((u16)(zr.w & 0xffffu));
            acc1.w += a * bf2f((u16)(zr.w >> 16));
        }
    }
    *reinterpret_cast<f32x4*>(op)     = acc0;
    *reinterpret_cast<f32x4*>(op + 4) = acc1;
}

// ---------------------------------------------------------------------------
extern "C" void kernel_launch(void* const* d_in, const int* in_sizes, int n_in,
                              void* d_out, int out_size, void* d_ws, size_t ws_size,
                              hipStream_t stream) {
    const float* h      = (const float*)d_in[0];   // fp32 per reference
    const float* W      = (const float*)d_in[1];   // fp32
    const float* a_attn = (const float*)d_in[2];   // fp32
    const int* esrc     = (const int*)d_in[3];
    const int* edst     = (const int*)d_in[4];
    float* out          = (float*)d_out;           // fp32 output (reference dtype)

    char* ws = (char*)d_ws;
    u16*   z        = (u16*)ws;                         // 102,400,000 B
    float* s_node   = (float*)(ws + 102400000);         //   3,200,000 B
    int*   counts   = (int*)(ws + 105600000);           //      80,000 B
    int*   offsets  = (int*)(ws + 105680000);           //      80,016 B
    int*   cursor   = (int*)(ws + 105760016);           //      80,000 B
    int*   ssrc     = (int*)(ws + 105840016);           //   1,280,000 B
    u16*   wbf      = (u16*)(ws + 107120016);           //     786,432 B -> 107.9 MB

    zero_kernel<<<(N_ARGS + 255) / 256, 256, 0, stream>>>(counts, N_ARGS);
    convert_w<<<(ZDIM * IN_DIM / 8 + 255) / 256, 256, 0, stream>>>(W, wbf);
    gemm_kernel<<<1568, 256, 0, stream>>>(h, wbf, a_attn, z, s_node);
    hist_kernel<<<(N_EDGES + 255) / 256, 256, 0, stream>>>(edst, counts);
    scan_kernel<<<1, 1024, 0, stream>>>(counts, offsets, cursor);
    scatter_kernel<<<(N_EDGES + 255) / 256, 256, 0, stream>>>(esrc, edst, cursor, ssrc);
    agg_kernel<<<(N_ARGS + 3) / 4, 256, 0, stream>>>(offsets, ssrc, s_node, z, out);
}